// Round 11
// baseline (167.044 us; speedup 1.0000x reference)
//
#include <hip/hip_runtime.h>

#define SL 256
#define RSTRIDE 312   // R-copy stride: >=288 needed (max s0+8 = 287), mult of 8;
                      // 156 words -> copy base banks 28c mod 32 all distinct

typedef _Float16 f16;
typedef _Float16 f16x8 __attribute__((ext_vector_type(8)));
typedef _Float16 f16x4 __attribute__((ext_vector_type(4)));
typedef float f32x4 __attribute__((ext_vector_type(4)));

// ---------------------------------------------------------------------------
// Filter MLP: one block per (l, sel); sel=0 -> X params, sel=1 -> Y params.
// Writes transposed f16 filters hT[sel][d][l] for fast R-table builds.
// ---------------------------------------------------------------------------
__global__ __launch_bounds__(64) void k_filters(
    const float* __restrict__ z,
    const float* __restrict__ Xw1, const float* __restrict__ Xb1,
    const float* __restrict__ Xw2, const float* __restrict__ Xb2,
    const float* __restrict__ Xw3, const float* __restrict__ Xb3,
    const float* __restrict__ Xwo, const float* __restrict__ Xfreq,
    const float* __restrict__ Yw1, const float* __restrict__ Yb1,
    const float* __restrict__ Yw2, const float* __restrict__ Yb2,
    const float* __restrict__ Yw3, const float* __restrict__ Yb3,
    const float* __restrict__ Ywo, const float* __restrict__ Yfreq,
    f16* __restrict__ hxT, f16* __restrict__ hyT)
{
    const int l = blockIdx.x;
    const int sel = blockIdx.y;
    const int t = threadIdx.x;
    const float* w1 = sel ? Yw1 : Xw1;  const float* b1 = sel ? Yb1 : Xb1;
    const float* w2 = sel ? Yw2 : Xw2;  const float* b2 = sel ? Yb2 : Xb2;
    const float* w3 = sel ? Yw3 : Xw3;  const float* b3 = sel ? Yb3 : Xb3;
    const float* wo = sel ? Ywo : Xwo;  const float* freq = sel ? Yfreq : Xfreq;
    f16* hT = sel ? hyT : hxT;

    __shared__ float zb[33];
    __shared__ float ha[64];
    __shared__ float hb[64];

    if (t < 33) zb[t] = z[l * 33 + t];
    __syncthreads();

    const float fr = freq[t];
    float s = b1[t];
    for (int k = 0; k < 33; ++k) s += zb[k] * w1[k * 64 + t];
    ha[t] = sinf(fr * s);
    __syncthreads();

    s = b2[t];
    for (int k = 0; k < 64; ++k) s += ha[k] * w2[k * 64 + t];
    hb[t] = sinf(fr * s);
    __syncthreads();

    s = b3[t];
    for (int k = 0; k < 64; ++k) s += hb[k] * w3[k * 64 + t];
    ha[t] = sinf(fr * s);
    __syncthreads();

    s = 0.f;
    for (int k = 0; k < 64; ++k) s += ha[k] * wo[k * 64 + t];

    const float MIN_DEC = -3.0701134573253937f;   // log(0.01)/1.5
    const float MAX_DEC = -15.350567286626968f;   // log(0.01)/0.3
    float ad = fabsf(MIN_DEC + (MAX_DEC - MIN_DEC) * ((float)t / 63.0f));
    float tl = (float)l / 255.0f;
    hT[t * 256 + l] = (f16)(s * expf(-tl * ad));   // [d][l]
}

__device__ __forceinline__ f16x8 cvt8(float4 a, float4 b)
{
    f16x8 h;
    h[0] = (f16)a.x; h[1] = (f16)a.y; h[2] = (f16)a.z; h[3] = (f16)a.w;
    h[4] = (f16)b.x; h[5] = (f16)b.y; h[6] = (f16)b.z; h[7] = (f16)b.w;
    return h;
}

// ---------------------------------------------------------------------------
// R-copy Toeplitz table: 8 shift-staggered copies of reversed zero-padded
// filter column so every Toeplitz fragment is one aligned ds_read_b128.
//   Rfull[u] = (u<=255) ? h[255-u] : 0 ;  R[c*RSTRIDE+k] = Rfull[k+c]
// Fragment T[row][k] = h[row-k] = Rfull[255-row+k]:
//   s0 = 255-row+k0 ; c = s0&7 ; f16x8 at R[c*RSTRIDE + (s0-c)]
// ---------------------------------------------------------------------------
template<int NT>
__device__ __forceinline__ void build_R(f16* R, const f16* __restrict__ hc,
                                        int tid)
{
    for (int idx = tid; idx < 8 * RSTRIDE; idx += NT) {
        int c = idx / RSTRIDE;
        int k = idx - c * RSTRIDE;
        int u = k + c;
        R[idx] = (u <= 255) ? hc[255 - u] : (f16)0.f;
    }
}

// raw workgroup barrier that does NOT drain vmcnt: LDS ordering only.
// (__syncthreads would emit s_waitcnt vmcnt(0), stalling in-flight x loads
//  and out-stores.)
__device__ __forceinline__ void bar_lgkm()
{
    asm volatile("s_waitcnt lgkmcnt(0)" ::: "memory");
    __builtin_amdgcn_s_barrier();
    __builtin_amdgcn_sched_barrier(0);
}

// ---------------------------------------------------------------------------
// 2-CHUNK PIPELINED ONE-BLOCK-PER-BD kernel (session-best, round 8).
// grid 256 x 1024 thr (16 waves = 16 waves/CU, one block per CU).
// j in 2 chunks of 128 cols, double-buffered LDS M:
//   p1(0) |B| {p2(0); cvt q1; p1(1)} |B| p2(1)
// x fetched exactly once: 16 float4/wave issued up front (SB(0) pin); the
// compiler retires q0 into axs early and keeps q1 (32 VGPR) in flight
// across p2(c0) -- 92-reg economy that exactly fits 16 waves/CU.  Raw
// lgkm-only barriers never drain vmcnt -> prefetch + out-stores stay
// outstanding across phase boundaries.  FETCH/WRITE at compulsory floor.
//
// p1 chunk jc: wave owns p-rows [16w,16w+16); j-tiles c8=0..7
//   (j=128jc+16c8+ln); active q-steps s <= 4jc+(c8>>1); 20/52 MFMA/wave.
// p2 chunk jc: wave = (igrp=wave>>1, 32 i-rows) x (jgrp=wave&1, 64 j-cols);
//   causal nst = igrp+1 exactly; early igrp waves reach their epilogue
//   first -> write traffic drip-feeds through the region.
// ---------------------------------------------------------------------------
template<int JC>
__device__ __forceinline__ void p1_work(
    const f16x8* axs, const f16* __restrict__ Ry, f16* __restrict__ buf,
    int wave, int ln, int quad)
{
    f32x4 acc[8];
#pragma unroll
    for (int t = 0; t < 8; ++t) acc[t] = (f32x4){0.f, 0.f, 0.f, 0.f};

#pragma unroll
    for (int s = 0; s <= 4 * JC + 3; ++s) {
        const int q0 = s * 32;
#pragma unroll
        for (int c8 = 0; c8 < 8; ++c8) {
            if (s <= 4 * JC + (c8 >> 1)) {        // compile-time fold
                const int j = JC * 128 + c8 * 16 + ln;
                const int s0 = 255 - j + q0 + quad * 8;
                const int c = s0 & 7;
                f16x8 bf = *(const f16x8*)&Ry[c * RSTRIDE + (s0 - c)];
                acc[c8] = __builtin_amdgcn_mfma_f32_16x16x32_f16(
                    axs[s], bf, acc[c8], 0, 0, 0);
            }
        }
    }
    // write M chunk to LDS: local (jl, p) at buf[jl*256 + (p ^ ((jl&7)<<3))]
#pragma unroll
    for (int c8 = 0; c8 < 8; ++c8) {
        const int jl = c8 * 16 + ln;
        const int pb = wave * 16 + quad * 4;
        f32x4 a = acc[c8];
        f16x4 v;
        v[0] = (f16)a[0]; v[1] = (f16)a[1];
        v[2] = (f16)a[2]; v[3] = (f16)a[3];
        *(f16x4*)&buf[jl * 256 + (pb ^ ((jl & 7) << 3))] = v;
    }
}

template<int JC>
__device__ __forceinline__ void p2_chunk(
    const f16* __restrict__ buf, const f16* __restrict__ Rx,
    const float* __restrict__ xbd, float* __restrict__ obd, float bv,
    int igrp, int jgrp, int ln, int quad)
{
    f32x4 acc[8];
#pragma unroll
    for (int t = 0; t < 8; ++t) acc[t] = (f32x4){0.f, 0.f, 0.f, 0.f};

    const int nst = igrp + 1;                 // causal p-step bound (exact)
    for (int s = 0; s < nst; ++s) {
        const int p0 = s * 32;
        f16x8 af[4];
#pragma unroll
        for (int jt = 0; jt < 4; ++jt) {      // A = M[jl][p]
            const int jl = jgrp * 64 + jt * 16 + ln;
            const int off = (p0 + quad * 8) ^ ((jl & 7) << 3);
            af[jt] = *(const f16x8*)&buf[jl * 256 + off];
        }
#pragma unroll
        for (int ct = 0; ct < 2; ++ct) {      // B[p][i] = hx[i-p]
            const int i = igrp * 32 + ct * 16 + ln;
            const int s0 = 255 - i + p0 + quad * 8;
            const int c = s0 & 7;
            f16x8 bf = *(const f16x8*)&Rx[c * RSTRIDE + (s0 - c)];
#pragma unroll
            for (int jt = 0; jt < 4; ++jt)
                acc[ct * 4 + jt] = __builtin_amdgcn_mfma_f32_16x16x32_f16(
                    af[jt], bf, acc[ct * 4 + jt], 0, 0, 0);
        }
    }

    // epilogue: out[i][j..j+3] = acc/512 + x*bias  (float4)
    const float sc = 1.0f / 512.0f;
#pragma unroll
    for (int ct = 0; ct < 2; ++ct) {
        const int i = igrp * 32 + ct * 16 + ln;
#pragma unroll
        for (int jt = 0; jt < 4; ++jt) {
            const int j = JC * 128 + jgrp * 64 + jt * 16 + quad * 4;
            f32x4 a = acc[ct * 4 + jt];
            float4 xv = *(const float4*)(xbd + i * SL + j);
            float4 o;
            o.x = a[0] * sc + xv.x * bv;
            o.y = a[1] * sc + xv.y * bv;
            o.z = a[2] * sc + xv.z * bv;
            o.w = a[3] * sc + xv.w * bv;
            *(float4*)(obd + i * SL + j) = o;
        }
    }
}

__global__ __launch_bounds__(1024, 4) void k_pipe(
    const float* __restrict__ x, const f16* __restrict__ hxT,
    const f16* __restrict__ hyT, const float* __restrict__ bias,
    float* __restrict__ out)
{
    extern __shared__ __align__(16) f16 smem[];
    f16* buf0 = smem;                       // [128][256] chunk-0 M
    f16* buf1 = smem + 128 * 256;           // [128][256] chunk-1 M
    f16* Ry   = smem + 2 * 128 * 256;
    f16* Rx   = Ry + 8 * RSTRIDE;

    const int bd = blockIdx.x;              // b*64 + d
    const int d  = bd & 63;
    const int tid  = threadIdx.x;
    const int lane = tid & 63;
    const int wave = tid >> 6;              // 0..15
    const int ln   = lane & 15;
    const int quad = lane >> 4;
    const int igrp = wave >> 1;             // p2: 8 i-groups of 32 rows
    const int jgrp = wave & 1;              // p2: 2 j-groups of 64 cols

    const float* xbd = x + (size_t)bd * (SL * SL);
    float* obd = out + (size_t)bd * (SL * SL);

    build_R<1024>(Ry, hyT + d * 256, tid);
    build_R<1024>(Rx, hxT + d * 256, tid);

    const float* xr = xbd + (wave * 16 + ln) * SL + quad * 8;
    const float bv = bias[d];

    // ---- issue the ENTIRE x row (16 float4) up front; pin with SB(0) -----
    float4 q[16];
#pragma unroll
    for (int s = 0; s < 8; ++s) {
        q[2 * s]     = *(const float4*)(xr + s * 32);
        q[2 * s + 1] = *(const float4*)(xr + s * 32 + 4);
    }
    __builtin_amdgcn_sched_barrier(0);      // loads stay issued here

    f16x8 axs[8];
#pragma unroll
    for (int s = 0; s < 4; ++s)             // waits first 8 loads only
        axs[s] = cvt8(q[2 * s], q[2 * s + 1]);

    bar_lgkm();                             // R tables ready; q1 in flight

    p1_work<0>(axs, Ry, buf0, wave, ln, quad);

    bar_lgkm();                             // buf0 ready; q1 still in flight

    p2_chunk<0>(buf0, Rx, xbd, obd, bv, igrp, jgrp, ln, quad);

#pragma unroll
    for (int s = 4; s < 8; ++s)             // q1 landed during p1/p2(c0)
        axs[s] = cvt8(q[2 * s], q[2 * s + 1]);

    p1_work<1>(axs, Ry, buf1, wave, ln, quad);

    bar_lgkm();                             // buf1 ready (out-stores may fly)

    p2_chunk<1>(buf1, Rx, xbd, obd, bv, igrp, jgrp, ln, quad);
}

// ---------------------------------------------------------------------------
// FALLBACK (if dynamic-LDS attribute fails): round-2 fused j-split kernel.
// ---------------------------------------------------------------------------
template<int J0>
__device__ __forceinline__ void phase1(
    const float* __restrict__ xr0, const float* __restrict__ xr1,
    const f16* __restrict__ R, f32x4 (&acc)[16], int ln, int quad)
{
    constexpr int QS = (J0 == 0) ? 4 : 8;
    float4 a0 = *(const float4*)xr0;
    float4 a1 = *(const float4*)(xr0 + 4);
    float4 b0 = *(const float4*)xr1;
    float4 b1 = *(const float4*)(xr1 + 4);

#pragma unroll
    for (int s = 0; s < QS; ++s) {
        const int q0 = s * 32;
        f16x8 af0 = cvt8(a0, a1);
        f16x8 af1 = cvt8(b0, b1);
        if (s + 1 < QS) {
            a0 = *(const float4*)(xr0 + q0 + 32);
            a1 = *(const float4*)(xr0 + q0 + 36);
            b0 = *(const float4*)(xr1 + q0 + 32);
            b1 = *(const float4*)(xr1 + q0 + 36);
        }
#pragma unroll
        for (int c8 = 0; c8 < 8; ++c8) {
            if (32 * s <= J0 + c8 * 16 + 15) {
                int j = J0 + c8 * 16 + ln;
                int s0 = 255 - j + q0 + quad * 8;
                int c = s0 & 7;
                f16x8 bf = *(const f16x8*)&R[c * RSTRIDE + (s0 - c)];
                acc[c8] = __builtin_amdgcn_mfma_f32_16x16x32_f16(
                    af0, bf, acc[c8], 0, 0, 0);
                acc[8 + c8] = __builtin_amdgcn_mfma_f32_16x16x32_f16(
                    af1, bf, acc[8 + c8], 0, 0, 0);
            }
        }
    }
}

__global__ __launch_bounds__(512, 4) void k_fused(
    const float* __restrict__ x, const f16* __restrict__ hxT,
    const f16* __restrict__ hyT, const float* __restrict__ bias,
    float* __restrict__ out)
{
    const int bd = blockIdx.x & 255;
    const int j0 = (blockIdx.x >> 8) << 7;
    const int d  = bd & 63;
    const int tid  = threadIdx.x;
    const int lane = tid & 63;
    const int wave = tid >> 6;
    const int ln   = lane & 15;
    const int quad = lane >> 4;

    __shared__ __align__(16) f16 tmp[128 * 256];
    __shared__ __align__(16) f16 R[8 * RSTRIDE];

    const float* xbd = x + (size_t)bd * (SL * SL);

    build_R<512>(R, hyT + d * 256, tid);

    f32x4 acc[16];
#pragma unroll
    for (int a = 0; a < 16; ++a) acc[a] = (f32x4){0.f, 0.f, 0.f, 0.f};

    __syncthreads();

    {
        const float* xr0 = xbd + (wave * 32 + ln) * SL + quad * 8;
        const float* xr1 = xr0 + 16 * SL;
        if (j0 == 0) phase1<0>(xr0, xr1, R, acc, ln, quad);
        else         phase1<128>(xr0, xr1, R, acc, ln, quad);

#pragma unroll
        for (int r = 0; r < 2; ++r)
#pragma unroll
            for (int c8 = 0; c8 < 8; ++c8) {
                int jl = c8 * 16 + ln;
                int pb = wave * 32 + r * 16 + quad * 4;
                f32x4 a = acc[r * 8 + c8];
                f16x4 v;
                v[0] = (f16)a[0]; v[1] = (f16)a[1];
                v[2] = (f16)a[2]; v[3] = (f16)a[3];
                *(f16x4*)&tmp[jl * 256 + (pb ^ ((jl & 7) << 3))] = v;
            }
    }

    __syncthreads();
    build_R<512>(R, hxT + d * 256, tid);
#pragma unroll
    for (int a = 0; a < 16; ++a) acc[a] = (f32x4){0.f, 0.f, 0.f, 0.f};
    __syncthreads();

    const int igrp = wave & 3;
    const int jgrp = wave >> 2;
    const int nst = (igrp + 1) * 2;
    for (int s = 0; s < nst; ++s) {
        const int p0 = s * 32;
        f16x8 af[4];
#pragma unroll
        for (int rt = 0; rt < 4; ++rt) {
            int jl = jgrp * 64 + rt * 16 + ln;
            int off = (p0 + quad * 8) ^ ((jl & 7) << 3);
            af[rt] = *(const f16x8*)&tmp[jl * 256 + off];
        }
#pragma unroll
        for (int ct = 0; ct < 4; ++ct) {
            if (p0 <= igrp * 64 + ct * 16 + 15) {
                int i = igrp * 64 + ct * 16 + ln;
                int s0 = 255 - i + p0 + quad * 8;
                int c = s0 & 7;
                f16x8 bf = *(const f16x8*)&R[c * RSTRIDE + (s0 - c)];
#pragma unroll
                for (int rt = 0; rt < 4; ++rt)
                    acc[rt * 4 + ct] = __builtin_amdgcn_mfma_f32_16x16x32_f16(
                        af[rt], bf, acc[rt * 4 + ct], 0, 0, 0);
            }
        }
    }

    const float bv = bias[d];
    const float sc = 1.0f / 512.0f;
    float* obd = out + (size_t)bd * (SL * SL);
#pragma unroll
    for (int rt = 0; rt < 4; ++rt)
#pragma unroll
        for (int ct = 0; ct < 4; ++ct) {
            int i = igrp * 64 + ct * 16 + ln;
            int j = j0 + jgrp * 64 + rt * 16 + quad * 4;
            f32x4 a = acc[rt * 4 + ct];
            float4 xv = *(const float4*)(xbd + i * SL + j);
            float4 o;
            o.x = a[0] * sc + xv.x * bv;
            o.y = a[1] * sc + xv.y * bv;
            o.z = a[2] * sc + xv.z * bv;
            o.w = a[3] * sc + xv.w * bv;
            *(float4*)(obd + i * SL + j) = o;
        }
}

extern "C" void kernel_launch(void* const* d_in, const int* in_sizes, int n_in,
                              void* d_out, int out_size, void* d_ws, size_t ws_size,
                              hipStream_t stream)
{
    (void)in_sizes; (void)n_in; (void)out_size; (void)ws_size;
    const float* x     = (const float*)d_in[0];
    const float* z     = (const float*)d_in[1];
    const float* Xw1   = (const float*)d_in[2];
    const float* Xb1   = (const float*)d_in[3];
    const float* Xw2   = (const float*)d_in[4];
    const float* Xb2   = (const float*)d_in[5];
    const float* Xw3   = (const float*)d_in[6];
    const float* Xb3   = (const float*)d_in[7];
    const float* Xwo   = (const float*)d_in[8];
    const float* Xfreq = (const float*)d_in[9];
    const float* Yw1   = (const float*)d_in[10];
    const float* Yb1   = (const float*)d_in[11];
    const float* Yw2   = (const float*)d_in[12];
    const float* Yb2   = (const float*)d_in[13];
    const float* Yw3   = (const float*)d_in[14];
    const float* Yb3   = (const float*)d_in[15];
    const float* Ywo   = (const float*)d_in[16];
    const float* Yfreq = (const float*)d_in[17];
    const float* bias  = (const float*)d_in[18];

    f16* hxT = (f16*)d_ws;                 // [64][256] f16
    f16* hyT = hxT + 64 * 256;             // [64][256] f16

    k_filters<<<dim3(256, 2), 64, 0, stream>>>(
        z, Xw1, Xb1, Xw2, Xb2, Xw3, Xb3, Xwo, Xfreq,
        Yw1, Yb1, Yw2, Yb2, Yw3, Yb3, Ywo, Yfreq, hxT, hyT);

    const int dyn_lds = (2 * 128 * 256 + 2 * 8 * RSTRIDE) * (int)sizeof(f16); // 141056
    static hipError_t attr_rc = hipFuncSetAttribute(
        (const void*)k_pipe, hipFuncAttributeMaxDynamicSharedMemorySize, dyn_lds);

    if (attr_rc == hipSuccess) {
        k_pipe<<<256, 1024, dyn_lds, stream>>>(x, hxT, hyT, bias, (float*)d_out);
    } else {
        k_fused<<<512, 512, 0, stream>>>(x, hxT, hyT, bias, (float*)d_out);
    }
}

// Round 12
// 166.977 us; speedup vs baseline: 1.0004x; 1.0004x over previous
//
#include <hip/hip_runtime.h>

#define SL 256
#define RSTRIDE 312   // R-copy stride: >=288 needed (max s0+8 = 287), mult of 8;
                      // 156 words -> copy base banks 28c mod 32 all distinct

typedef _Float16 f16;
typedef _Float16 f16x8 __attribute__((ext_vector_type(8)));
typedef _Float16 f16x4 __attribute__((ext_vector_type(4)));
typedef float f32x4 __attribute__((ext_vector_type(4)));

// ---------------------------------------------------------------------------
// Filter MLP: one block per (l, sel); sel=0 -> X params, sel=1 -> Y params.
// Writes transposed f16 filters hT[sel][d][l] for fast R-table builds.
// ---------------------------------------------------------------------------
__global__ __launch_bounds__(64) void k_filters(
    const float* __restrict__ z,
    const float* __restrict__ Xw1, const float* __restrict__ Xb1,
    const float* __restrict__ Xw2, const float* __restrict__ Xb2,
    const float* __restrict__ Xw3, const float* __restrict__ Xb3,
    const float* __restrict__ Xwo, const float* __restrict__ Xfreq,
    const float* __restrict__ Yw1, const float* __restrict__ Yb1,
    const float* __restrict__ Yw2, const float* __restrict__ Yb2,
    const float* __restrict__ Yw3, const float* __restrict__ Yb3,
    const float* __restrict__ Ywo, const float* __restrict__ Yfreq,
    f16* __restrict__ hxT, f16* __restrict__ hyT)
{
    const int l = blockIdx.x;
    const int sel = blockIdx.y;
    const int t = threadIdx.x;
    const float* w1 = sel ? Yw1 : Xw1;  const float* b1 = sel ? Yb1 : Xb1;
    const float* w2 = sel ? Yw2 : Xw2;  const float* b2 = sel ? Yb2 : Xb2;
    const float* w3 = sel ? Yw3 : Xw3;  const float* b3 = sel ? Yb3 : Xb3;
    const float* wo = sel ? Ywo : Xwo;  const float* freq = sel ? Yfreq : Xfreq;
    f16* hT = sel ? hyT : hxT;

    __shared__ float zb[33];
    __shared__ float ha[64];
    __shared__ float hb[64];

    if (t < 33) zb[t] = z[l * 33 + t];
    __syncthreads();

    const float fr = freq[t];
    float s = b1[t];
    for (int k = 0; k < 33; ++k) s += zb[k] * w1[k * 64 + t];
    ha[t] = sinf(fr * s);
    __syncthreads();

    s = b2[t];
    for (int k = 0; k < 64; ++k) s += ha[k] * w2[k * 64 + t];
    hb[t] = sinf(fr * s);
    __syncthreads();

    s = b3[t];
    for (int k = 0; k < 64; ++k) s += hb[k] * w3[k * 64 + t];
    ha[t] = sinf(fr * s);
    __syncthreads();

    s = 0.f;
    for (int k = 0; k < 64; ++k) s += ha[k] * wo[k * 64 + t];

    const float MIN_DEC = -3.0701134573253937f;   // log(0.01)/1.5
    const float MAX_DEC = -15.350567286626968f;   // log(0.01)/0.3
    float ad = fabsf(MIN_DEC + (MAX_DEC - MIN_DEC) * ((float)t / 63.0f));
    float tl = (float)l / 255.0f;
    hT[t * 256 + l] = (f16)(s * expf(-tl * ad));   // [d][l]
}

__device__ __forceinline__ f16x8 cvt8(float4 a, float4 b)
{
    f16x8 h;
    h[0] = (f16)a.x; h[1] = (f16)a.y; h[2] = (f16)a.z; h[3] = (f16)a.w;
    h[4] = (f16)b.x; h[5] = (f16)b.y; h[6] = (f16)b.z; h[7] = (f16)b.w;
    return h;
}

// ---------------------------------------------------------------------------
// R-copy Toeplitz table: 8 shift-staggered copies of reversed zero-padded
// filter column so every Toeplitz fragment is one aligned ds_read_b128.
//   Rfull[u] = (u<=255) ? h[255-u] : 0 ;  R[c*RSTRIDE+k] = Rfull[k+c]
// Fragment T[row][k] = h[row-k] = Rfull[255-row+k]:
//   s0 = 255-row+k0 ; c = s0&7 ; f16x8 at R[c*RSTRIDE + (s0-c)]
// ---------------------------------------------------------------------------
template<int NT>
__device__ __forceinline__ void build_R(f16* R, const f16* __restrict__ hc,
                                        int tid)
{
    for (int idx = tid; idx < 8 * RSTRIDE; idx += NT) {
        int c = idx / RSTRIDE;
        int k = idx - c * RSTRIDE;
        int u = k + c;
        R[idx] = (u <= 255) ? hc[255 - u] : (f16)0.f;
    }
}

// raw workgroup barrier that does NOT drain vmcnt: LDS ordering only.
// (__syncthreads would emit s_waitcnt vmcnt(0), stalling in-flight x loads
//  and out-stores.)
__device__ __forceinline__ void bar_lgkm()
{
    asm volatile("s_waitcnt lgkmcnt(0)" ::: "memory");
    __builtin_amdgcn_s_barrier();
    __builtin_amdgcn_sched_barrier(0);
}

// ---------------------------------------------------------------------------
// 2-CHUNK PIPELINED ONE-BLOCK-PER-BD kernel (r8 structure + LAZY CVT).
// grid 256 x 1024 thr (16 waves = 16 waves/CU, one block per CU).
// j in 2 chunks of 128 cols, double-buffered LDS M:
//   p1(0) |B| {p2(0); p1(1)} |B| p2(1)
// x fetched exactly once: 16 float4/wave issued up front (SB(0) pin).
// LAZY CVT: axs[s] is converted from q inside the p1 s-loop (CVT_FROM
// template bound), so the first MFMA waits vmcnt for only 2 loads instead
// of all 8 -- startup bubble ~5.1us -> ~1.3us.  axs[0..3] persist from
// chunk 0 into chunk 1's p1 (q0 regs retire at first use; q1 stays in
// flight across p2(c0)).  Raw lgkm-only barriers never drain vmcnt.
// FETCH/WRITE at compulsory floor.  Bit-identical output (pure reorder).
//
// p1 chunk jc: wave owns p-rows [16w,16w+16); j-tiles c8=0..7
//   (j=128jc+16c8+ln); active q-steps s <= 4jc+(c8>>1); 20/52 MFMA/wave.
// p2 chunk jc: wave = (igrp=wave>>1, 32 i-rows) x (jgrp=wave&1, 64 j-cols);
//   causal nst = igrp+1 exactly; early igrp waves reach their epilogue
//   first -> write traffic drip-feeds through the region.
// ---------------------------------------------------------------------------
template<int JC, int CVT_FROM>
__device__ __forceinline__ void p1_work(
    const float4* q, f16x8 (&axs)[8], const f16* __restrict__ Ry,
    f16* __restrict__ buf, int wave, int ln, int quad)
{
    f32x4 acc[8];
#pragma unroll
    for (int t = 0; t < 8; ++t) acc[t] = (f32x4){0.f, 0.f, 0.f, 0.f};

#pragma unroll
    for (int s = 0; s <= 4 * JC + 3; ++s) {
        if (s >= CVT_FROM)                        // lazy convert: waits only
            axs[s] = cvt8(q[2 * s], q[2 * s + 1]); // loads 2s,2s+1 (vmcnt)
        const int q0 = s * 32;
#pragma unroll
        for (int c8 = 0; c8 < 8; ++c8) {
            if (s <= 4 * JC + (c8 >> 1)) {        // compile-time fold
                const int j = JC * 128 + c8 * 16 + ln;
                const int s0 = 255 - j + q0 + quad * 8;
                const int c = s0 & 7;
                f16x8 bf = *(const f16x8*)&Ry[c * RSTRIDE + (s0 - c)];
                acc[c8] = __builtin_amdgcn_mfma_f32_16x16x32_f16(
                    axs[s], bf, acc[c8], 0, 0, 0);
            }
        }
    }
    // write M chunk to LDS: local (jl, p) at buf[jl*256 + (p ^ ((jl&7)<<3))]
#pragma unroll
    for (int c8 = 0; c8 < 8; ++c8) {
        const int jl = c8 * 16 + ln;
        const int pb = wave * 16 + quad * 4;
        f32x4 a = acc[c8];
        f16x4 v;
        v[0] = (f16)a[0]; v[1] = (f16)a[1];
        v[2] = (f16)a[2]; v[3] = (f16)a[3];
        *(f16x4*)&buf[jl * 256 + (pb ^ ((jl & 7) << 3))] = v;
    }
}

template<int JC>
__device__ __forceinline__ void p2_chunk(
    const f16* __restrict__ buf, const f16* __restrict__ Rx,
    const float* __restrict__ xbd, float* __restrict__ obd, float bv,
    int igrp, int jgrp, int ln, int quad)
{
    f32x4 acc[8];
#pragma unroll
    for (int t = 0; t < 8; ++t) acc[t] = (f32x4){0.f, 0.f, 0.f, 0.f};

    const int nst = igrp + 1;                 // causal p-step bound (exact)
    for (int s = 0; s < nst; ++s) {
        const int p0 = s * 32;
        f16x8 af[4];
#pragma unroll
        for (int jt = 0; jt < 4; ++jt) {      // A = M[jl][p]
            const int jl = jgrp * 64 + jt * 16 + ln;
            const int off = (p0 + quad * 8) ^ ((jl & 7) << 3);
            af[jt] = *(const f16x8*)&buf[jl * 256 + off];
        }
#pragma unroll
        for (int ct = 0; ct < 2; ++ct) {      // B[p][i] = hx[i-p]
            const int i = igrp * 32 + ct * 16 + ln;
            const int s0 = 255 - i + p0 + quad * 8;
            const int c = s0 & 7;
            f16x8 bf = *(const f16x8*)&Rx[c * RSTRIDE + (s0 - c)];
#pragma unroll
            for (int jt = 0; jt < 4; ++jt)
                acc[ct * 4 + jt] = __builtin_amdgcn_mfma_f32_16x16x32_f16(
                    af[jt], bf, acc[ct * 4 + jt], 0, 0, 0);
        }
    }

    // epilogue: out[i][j..j+3] = acc/512 + x*bias  (float4)
    const float sc = 1.0f / 512.0f;
#pragma unroll
    for (int ct = 0; ct < 2; ++ct) {
        const int i = igrp * 32 + ct * 16 + ln;
#pragma unroll
        for (int jt = 0; jt < 4; ++jt) {
            const int j = JC * 128 + jgrp * 64 + jt * 16 + quad * 4;
            f32x4 a = acc[ct * 4 + jt];
            float4 xv = *(const float4*)(xbd + i * SL + j);
            float4 o;
            o.x = a[0] * sc + xv.x * bv;
            o.y = a[1] * sc + xv.y * bv;
            o.z = a[2] * sc + xv.z * bv;
            o.w = a[3] * sc + xv.w * bv;
            *(float4*)(obd + i * SL + j) = o;
        }
    }
}

__global__ __launch_bounds__(1024, 4) void k_pipe(
    const float* __restrict__ x, const f16* __restrict__ hxT,
    const f16* __restrict__ hyT, const float* __restrict__ bias,
    float* __restrict__ out)
{
    extern __shared__ __align__(16) f16 smem[];
    f16* buf0 = smem;                       // [128][256] chunk-0 M
    f16* buf1 = smem + 128 * 256;           // [128][256] chunk-1 M
    f16* Ry   = smem + 2 * 128 * 256;
    f16* Rx   = Ry + 8 * RSTRIDE;

    const int bd = blockIdx.x;              // b*64 + d
    const int d  = bd & 63;
    const int tid  = threadIdx.x;
    const int lane = tid & 63;
    const int wave = tid >> 6;              // 0..15
    const int ln   = lane & 15;
    const int quad = lane >> 4;
    const int igrp = wave >> 1;             // p2: 8 i-groups of 32 rows
    const int jgrp = wave & 1;              // p2: 2 j-groups of 64 cols

    const float* xbd = x + (size_t)bd * (SL * SL);
    float* obd = out + (size_t)bd * (SL * SL);

    build_R<1024>(Ry, hyT + d * 256, tid);
    build_R<1024>(Rx, hxT + d * 256, tid);

    const float* xr = xbd + (wave * 16 + ln) * SL + quad * 8;
    const float bv = bias[d];

    // ---- issue the ENTIRE x row (16 float4) up front; pin with SB(0) -----
    float4 q[16];
#pragma unroll
    for (int s = 0; s < 8; ++s) {
        q[2 * s]     = *(const float4*)(xr + s * 32);
        q[2 * s + 1] = *(const float4*)(xr + s * 32 + 4);
    }
    __builtin_amdgcn_sched_barrier(0);      // loads stay issued here

    f16x8 axs[8];

    bar_lgkm();                             // R tables ready (lgkm only --
                                            // no vmcnt wait before barrier)

    // p1(c0): lazy cvt inside the loop -> first MFMA after 2 loads
    p1_work<0, 0>(q, axs, Ry, buf0, wave, ln, quad);

    bar_lgkm();                             // buf0 ready; q1 in flight

    p2_chunk<0>(buf0, Rx, xbd, obd, bv, igrp, jgrp, ln, quad);

    // p1(c1): axs[0..3] persist from c0; axs[4..7] lazy-cvt (q1 landed
    // during p2(c0), waits are cheap)
    p1_work<1, 4>(q, axs, Ry, buf1, wave, ln, quad);

    bar_lgkm();                             // buf1 ready (out-stores may fly)

    p2_chunk<1>(buf1, Rx, xbd, obd, bv, igrp, jgrp, ln, quad);
}

// ---------------------------------------------------------------------------
// FALLBACK (if dynamic-LDS attribute fails): round-2 fused j-split kernel.
// ---------------------------------------------------------------------------
template<int J0>
__device__ __forceinline__ void phase1(
    const float* __restrict__ xr0, const float* __restrict__ xr1,
    const f16* __restrict__ R, f32x4 (&acc)[16], int ln, int quad)
{
    constexpr int QS = (J0 == 0) ? 4 : 8;
    float4 a0 = *(const float4*)xr0;
    float4 a1 = *(const float4*)(xr0 + 4);
    float4 b0 = *(const float4*)xr1;
    float4 b1 = *(const float4*)(xr1 + 4);

#pragma unroll
    for (int s = 0; s < QS; ++s) {
        const int q0 = s * 32;
        f16x8 af0 = cvt8(a0, a1);
        f16x8 af1 = cvt8(b0, b1);
        if (s + 1 < QS) {
            a0 = *(const float4*)(xr0 + q0 + 32);
            a1 = *(const float4*)(xr0 + q0 + 36);
            b0 = *(const float4*)(xr1 + q0 + 32);
            b1 = *(const float4*)(xr1 + q0 + 36);
        }
#pragma unroll
        for (int c8 = 0; c8 < 8; ++c8) {
            if (32 * s <= J0 + c8 * 16 + 15) {
                int j = J0 + c8 * 16 + ln;
                int s0 = 255 - j + q0 + quad * 8;
                int c = s0 & 7;
                f16x8 bf = *(const f16x8*)&R[c * RSTRIDE + (s0 - c)];
                acc[c8] = __builtin_amdgcn_mfma_f32_16x16x32_f16(
                    af0, bf, acc[c8], 0, 0, 0);
                acc[8 + c8] = __builtin_amdgcn_mfma_f32_16x16x32_f16(
                    af1, bf, acc[8 + c8], 0, 0, 0);
            }
        }
    }
}

__global__ __launch_bounds__(512, 4) void k_fused(
    const float* __restrict__ x, const f16* __restrict__ hxT,
    const f16* __restrict__ hyT, const float* __restrict__ bias,
    float* __restrict__ out)
{
    const int bd = blockIdx.x & 255;
    const int j0 = (blockIdx.x >> 8) << 7;
    const int d  = bd & 63;
    const int tid  = threadIdx.x;
    const int lane = tid & 63;
    const int wave = tid >> 6;
    const int ln   = lane & 15;
    const int quad = lane >> 4;

    __shared__ __align__(16) f16 tmp[128 * 256];
    __shared__ __align__(16) f16 R[8 * RSTRIDE];

    const float* xbd = x + (size_t)bd * (SL * SL);

    build_R<512>(R, hyT + d * 256, tid);

    f32x4 acc[16];
#pragma unroll
    for (int a = 0; a < 16; ++a) acc[a] = (f32x4){0.f, 0.f, 0.f, 0.f};

    __syncthreads();

    {
        const float* xr0 = xbd + (wave * 32 + ln) * SL + quad * 8;
        const float* xr1 = xr0 + 16 * SL;
        if (j0 == 0) phase1<0>(xr0, xr1, R, acc, ln, quad);
        else         phase1<128>(xr0, xr1, R, acc, ln, quad);

#pragma unroll
        for (int r = 0; r < 2; ++r)
#pragma unroll
            for (int c8 = 0; c8 < 8; ++c8) {
                int jl = c8 * 16 + ln;
                int pb = wave * 32 + r * 16 + quad * 4;
                f32x4 a = acc[r * 8 + c8];
                f16x4 v;
                v[0] = (f16)a[0]; v[1] = (f16)a[1];
                v[2] = (f16)a[2]; v[3] = (f16)a[3];
                *(f16x4*)&tmp[jl * 256 + (pb ^ ((jl & 7) << 3))] = v;
            }
    }

    __syncthreads();
    build_R<512>(R, hxT + d * 256, tid);
#pragma unroll
    for (int a = 0; a < 16; ++a) acc[a] = (f32x4){0.f, 0.f, 0.f, 0.f};
    __syncthreads();

    const int igrp = wave & 3;
    const int jgrp = wave >> 2;
    const int nst = (igrp + 1) * 2;
    for (int s = 0; s < nst; ++s) {
        const int p0 = s * 32;
        f16x8 af[4];
#pragma unroll
        for (int rt = 0; rt < 4; ++rt) {
            int jl = jgrp * 64 + rt * 16 + ln;
            int off = (p0 + quad * 8) ^ ((jl & 7) << 3);
            af[rt] = *(const f16x8*)&tmp[jl * 256 + off];
        }
#pragma unroll
        for (int ct = 0; ct < 4; ++ct) {
            if (p0 <= igrp * 64 + ct * 16 + 15) {
                int i = igrp * 64 + ct * 16 + ln;
                int s0 = 255 - i + p0 + quad * 8;
                int c = s0 & 7;
                f16x8 bf = *(const f16x8*)&R[c * RSTRIDE + (s0 - c)];
#pragma unroll
                for (int rt = 0; rt < 4; ++rt)
                    acc[rt * 4 + ct] = __builtin_amdgcn_mfma_f32_16x16x32_f16(
                        af[rt], bf, acc[rt * 4 + ct], 0, 0, 0);
            }
        }
    }

    const float bv = bias[d];
    const float sc = 1.0f / 512.0f;
    float* obd = out + (size_t)bd * (SL * SL);
#pragma unroll
    for (int rt = 0; rt < 4; ++rt)
#pragma unroll
        for (int ct = 0; ct < 4; ++ct) {
            int i = igrp * 64 + ct * 16 + ln;
            int j = j0 + jgrp * 64 + rt * 16 + quad * 4;
            f32x4 a = acc[rt * 4 + ct];
            float4 xv = *(const float4*)(xbd + i * SL + j);
            float4 o;
            o.x = a[0] * sc + xv.x * bv;
            o.y = a[1] * sc + xv.y * bv;
            o.z = a[2] * sc + xv.z * bv;
            o.w = a[3] * sc + xv.w * bv;
            *(float4*)(obd + i * SL + j) = o;
        }
}

extern "C" void kernel_launch(void* const* d_in, const int* in_sizes, int n_in,
                              void* d_out, int out_size, void* d_ws, size_t ws_size,
                              hipStream_t stream)
{
    (void)in_sizes; (void)n_in; (void)out_size; (void)ws_size;
    const float* x     = (const float*)d_in[0];
    const float* z     = (const float*)d_in[1];
    const float* Xw1   = (const float*)d_in[2];
    const float* Xb1   = (const float*)d_in[3];
    const float* Xw2   = (const float*)d_in[4];
    const float* Xb2   = (const float*)d_in[5];
    const float* Xw3   = (const float*)d_in[6];
    const float* Xb3   = (const float*)d_in[7];
    const float* Xwo   = (const float*)d_in[8];
    const float* Xfreq = (const float*)d_in[9];
    const float* Yw1   = (const float*)d_in[10];
    const float* Yb1   = (const float*)d_in[11];
    const float* Yw2   = (const float*)d_in[12];
    const float* Yb2   = (const float*)d_in[13];
    const float* Yw3   = (const float*)d_in[14];
    const float* Yb3   = (const float*)d_in[15];
    const float* Ywo   = (const float*)d_in[16];
    const float* Yfreq = (const float*)d_in[17];
    const float* bias  = (const float*)d_in[18];

    f16* hxT = (f16*)d_ws;                 // [64][256] f16
    f16* hyT = hxT + 64 * 256;             // [64][256] f16

    k_filters<<<dim3(256, 2), 64, 0, stream>>>(
        z, Xw1, Xb1, Xw2, Xb2, Xw3, Xb3, Xwo, Xfreq,
        Yw1, Yb1, Yw2, Yb2, Yw3, Yb3, Ywo, Yfreq, hxT, hyT);

    const int dyn_lds = (2 * 128 * 256 + 2 * 8 * RSTRIDE) * (int)sizeof(f16); // 141056
    static hipError_t attr_rc = hipFuncSetAttribute(
        (const void*)k_pipe, hipFuncAttributeMaxDynamicSharedMemorySize, dyn_lds);

    if (attr_rc == hipSuccess) {
        k_pipe<<<256, 1024, dyn_lds, stream>>>(x, hxT, hyT, bias, (float*)d_out);
    } else {
        k_fused<<<512, 512, 0, stream>>>(x, hxT, hyT, bias, (float*)d_out);
    }
}

// Round 13
// 162.775 us; speedup vs baseline: 1.0262x; 1.0258x over previous
//
#include <hip/hip_runtime.h>

#define SL 256
#define RSTRIDE 312   // R-copy stride: >=288 needed (max s0+8 = 287), mult of 8;
                      // 156 words -> copy base banks 28c mod 32 all distinct

typedef _Float16 f16;
typedef _Float16 f16x8 __attribute__((ext_vector_type(8)));
typedef _Float16 f16x4 __attribute__((ext_vector_type(4)));
typedef float f32x4 __attribute__((ext_vector_type(4)));

// ---------------------------------------------------------------------------
// Filter MLP: one block per (l, sel); sel=0 -> X params, sel=1 -> Y params.
// Writes transposed f16 filters hT[sel][d][l] for fast R-table builds.
// ---------------------------------------------------------------------------
__global__ __launch_bounds__(64) void k_filters(
    const float* __restrict__ z,
    const float* __restrict__ Xw1, const float* __restrict__ Xb1,
    const float* __restrict__ Xw2, const float* __restrict__ Xb2,
    const float* __restrict__ Xw3, const float* __restrict__ Xb3,
    const float* __restrict__ Xwo, const float* __restrict__ Xfreq,
    const float* __restrict__ Yw1, const float* __restrict__ Yb1,
    const float* __restrict__ Yw2, const float* __restrict__ Yb2,
    const float* __restrict__ Yw3, const float* __restrict__ Yb3,
    const float* __restrict__ Ywo, const float* __restrict__ Yfreq,
    f16* __restrict__ hxT, f16* __restrict__ hyT)
{
    const int l = blockIdx.x;
    const int sel = blockIdx.y;
    const int t = threadIdx.x;
    const float* w1 = sel ? Yw1 : Xw1;  const float* b1 = sel ? Yb1 : Xb1;
    const float* w2 = sel ? Yw2 : Xw2;  const float* b2 = sel ? Yb2 : Xb2;
    const float* w3 = sel ? Yw3 : Xw3;  const float* b3 = sel ? Yb3 : Xb3;
    const float* wo = sel ? Ywo : Xwo;  const float* freq = sel ? Yfreq : Xfreq;
    f16* hT = sel ? hyT : hxT;

    __shared__ float zb[33];
    __shared__ float ha[64];
    __shared__ float hb[64];

    if (t < 33) zb[t] = z[l * 33 + t];
    __syncthreads();

    const float fr = freq[t];
    float s = b1[t];
    for (int k = 0; k < 33; ++k) s += zb[k] * w1[k * 64 + t];
    ha[t] = sinf(fr * s);
    __syncthreads();

    s = b2[t];
    for (int k = 0; k < 64; ++k) s += ha[k] * w2[k * 64 + t];
    hb[t] = sinf(fr * s);
    __syncthreads();

    s = b3[t];
    for (int k = 0; k < 64; ++k) s += hb[k] * w3[k * 64 + t];
    ha[t] = sinf(fr * s);
    __syncthreads();

    s = 0.f;
    for (int k = 0; k < 64; ++k) s += ha[k] * wo[k * 64 + t];

    const float MIN_DEC = -3.0701134573253937f;   // log(0.01)/1.5
    const float MAX_DEC = -15.350567286626968f;   // log(0.01)/0.3
    float ad = fabsf(MIN_DEC + (MAX_DEC - MIN_DEC) * ((float)t / 63.0f));
    float tl = (float)l / 255.0f;
    hT[t * 256 + l] = (f16)(s * expf(-tl * ad));   // [d][l]
}

__device__ __forceinline__ f16x8 cvt8(float4 a, float4 b)
{
    f16x8 h;
    h[0] = (f16)a.x; h[1] = (f16)a.y; h[2] = (f16)a.z; h[3] = (f16)a.w;
    h[4] = (f16)b.x; h[5] = (f16)b.y; h[6] = (f16)b.z; h[7] = (f16)b.w;
    return h;
}

// ---------------------------------------------------------------------------
// R-copy Toeplitz table: 8 shift-staggered copies of reversed zero-padded
// filter column so every Toeplitz fragment is one aligned ds_read_b128.
//   Rfull[u] = (u<=255) ? h[255-u] : 0 ;  R[c*RSTRIDE+k] = Rfull[k+c]
// Fragment T[row][k] = h[row-k] = Rfull[255-row+k]:
//   s0 = 255-row+k0 ; c = s0&7 ; f16x8 at R[c*RSTRIDE + (s0-c)]
// ---------------------------------------------------------------------------
template<int NT>
__device__ __forceinline__ void build_R(f16* R, const f16* __restrict__ hc,
                                        int tid)
{
    for (int idx = tid; idx < 8 * RSTRIDE; idx += NT) {
        int c = idx / RSTRIDE;
        int k = idx - c * RSTRIDE;
        int u = k + c;
        R[idx] = (u <= 255) ? hc[255 - u] : (f16)0.f;
    }
}

// raw workgroup barrier that does NOT drain vmcnt: LDS ordering only.
// (__syncthreads would emit s_waitcnt vmcnt(0), stalling in-flight x loads
//  and out-stores.)
__device__ __forceinline__ void bar_lgkm()
{
    asm volatile("s_waitcnt lgkmcnt(0)" ::: "memory");
    __builtin_amdgcn_s_barrier();
    __builtin_amdgcn_sched_barrier(0);
}

// ---------------------------------------------------------------------------
// 2-CHUNK PIPELINED ONE-BLOCK-PER-BD kernel (session-best, round 8).
// grid 256 x 1024 thr (16 waves = 16 waves/CU, one block per CU).
// j in 2 chunks of 128 cols, double-buffered LDS M:
//   p1(0) |B| {p2(0); cvt q1; p1(1)} |B| p2(1)
// x fetched exactly once: 16 float4/wave issued up front (SB(0) pin); the
// compiler retires q0 into axs early and keeps q1 (32 VGPR) in flight
// across p2(c0) -- 92-reg economy that exactly fits 16 waves/CU.  Raw
// lgkm-only barriers never drain vmcnt -> prefetch + out-stores stay
// outstanding across phase boundaries.  FETCH/WRITE at compulsory floor.
// NOTE (r12): lazy-cvt inside the p1 loop regresses BYTES (WRITE 66->87 MB)
// -- the batched cvt placement below is load-retirement AND L2-residency
// optimal.  Do not reorder.
//
// p1 chunk jc: wave owns p-rows [16w,16w+16); j-tiles c8=0..7
//   (j=128jc+16c8+ln); active q-steps s <= 4jc+(c8>>1); 20/52 MFMA/wave.
// p2 chunk jc: wave = (igrp=wave>>1, 32 i-rows) x (jgrp=wave&1, 64 j-cols);
//   causal nst = igrp+1 exactly; early igrp waves reach their epilogue
//   first -> write traffic drip-feeds through the region.
// ---------------------------------------------------------------------------
template<int JC>
__device__ __forceinline__ void p1_work(
    const f16x8* axs, const f16* __restrict__ Ry, f16* __restrict__ buf,
    int wave, int ln, int quad)
{
    f32x4 acc[8];
#pragma unroll
    for (int t = 0; t < 8; ++t) acc[t] = (f32x4){0.f, 0.f, 0.f, 0.f};

#pragma unroll
    for (int s = 0; s <= 4 * JC + 3; ++s) {
        const int q0 = s * 32;
#pragma unroll
        for (int c8 = 0; c8 < 8; ++c8) {
            if (s <= 4 * JC + (c8 >> 1)) {        // compile-time fold
                const int j = JC * 128 + c8 * 16 + ln;
                const int s0 = 255 - j + q0 + quad * 8;
                const int c = s0 & 7;
                f16x8 bf = *(const f16x8*)&Ry[c * RSTRIDE + (s0 - c)];
                acc[c8] = __builtin_amdgcn_mfma_f32_16x16x32_f16(
                    axs[s], bf, acc[c8], 0, 0, 0);
            }
        }
    }
    // write M chunk to LDS: local (jl, p) at buf[jl*256 + (p ^ ((jl&7)<<3))]
#pragma unroll
    for (int c8 = 0; c8 < 8; ++c8) {
        const int jl = c8 * 16 + ln;
        const int pb = wave * 16 + quad * 4;
        f32x4 a = acc[c8];
        f16x4 v;
        v[0] = (f16)a[0]; v[1] = (f16)a[1];
        v[2] = (f16)a[2]; v[3] = (f16)a[3];
        *(f16x4*)&buf[jl * 256 + (pb ^ ((jl & 7) << 3))] = v;
    }
}

template<int JC>
__device__ __forceinline__ void p2_chunk(
    const f16* __restrict__ buf, const f16* __restrict__ Rx,
    const float* __restrict__ xbd, float* __restrict__ obd, float bv,
    int igrp, int jgrp, int ln, int quad)
{
    f32x4 acc[8];
#pragma unroll
    for (int t = 0; t < 8; ++t) acc[t] = (f32x4){0.f, 0.f, 0.f, 0.f};

    const int nst = igrp + 1;                 // causal p-step bound (exact)
    for (int s = 0; s < nst; ++s) {
        const int p0 = s * 32;
        f16x8 af[4];
#pragma unroll
        for (int jt = 0; jt < 4; ++jt) {      // A = M[jl][p]
            const int jl = jgrp * 64 + jt * 16 + ln;
            const int off = (p0 + quad * 8) ^ ((jl & 7) << 3);
            af[jt] = *(const f16x8*)&buf[jl * 256 + off];
        }
#pragma unroll
        for (int ct = 0; ct < 2; ++ct) {      // B[p][i] = hx[i-p]
            const int i = igrp * 32 + ct * 16 + ln;
            const int s0 = 255 - i + p0 + quad * 8;
            const int c = s0 & 7;
            f16x8 bf = *(const f16x8*)&Rx[c * RSTRIDE + (s0 - c)];
#pragma unroll
            for (int jt = 0; jt < 4; ++jt)
                acc[ct * 4 + jt] = __builtin_amdgcn_mfma_f32_16x16x32_f16(
                    af[jt], bf, acc[ct * 4 + jt], 0, 0, 0);
        }
    }

    // epilogue: out[i][j..j+3] = acc/512 + x*bias  (float4)
    const float sc = 1.0f / 512.0f;
#pragma unroll
    for (int ct = 0; ct < 2; ++ct) {
        const int i = igrp * 32 + ct * 16 + ln;
#pragma unroll
        for (int jt = 0; jt < 4; ++jt) {
            const int j = JC * 128 + jgrp * 64 + jt * 16 + quad * 4;
            f32x4 a = acc[ct * 4 + jt];
            float4 xv = *(const float4*)(xbd + i * SL + j);
            float4 o;
            o.x = a[0] * sc + xv.x * bv;
            o.y = a[1] * sc + xv.y * bv;
            o.z = a[2] * sc + xv.z * bv;
            o.w = a[3] * sc + xv.w * bv;
            *(float4*)(obd + i * SL + j) = o;
        }
    }
}

__global__ __launch_bounds__(1024, 4) void k_pipe(
    const float* __restrict__ x, const f16* __restrict__ hxT,
    const f16* __restrict__ hyT, const float* __restrict__ bias,
    float* __restrict__ out)
{
    extern __shared__ __align__(16) f16 smem[];
    f16* buf0 = smem;                       // [128][256] chunk-0 M
    f16* buf1 = smem + 128 * 256;           // [128][256] chunk-1 M
    f16* Ry   = smem + 2 * 128 * 256;
    f16* Rx   = Ry + 8 * RSTRIDE;

    const int bd = blockIdx.x;              // b*64 + d
    const int d  = bd & 63;
    const int tid  = threadIdx.x;
    const int lane = tid & 63;
    const int wave = tid >> 6;              // 0..15
    const int ln   = lane & 15;
    const int quad = lane >> 4;
    const int igrp = wave >> 1;             // p2: 8 i-groups of 32 rows
    const int jgrp = wave & 1;              // p2: 2 j-groups of 64 cols

    const float* xbd = x + (size_t)bd * (SL * SL);
    float* obd = out + (size_t)bd * (SL * SL);

    build_R<1024>(Ry, hyT + d * 256, tid);
    build_R<1024>(Rx, hxT + d * 256, tid);

    const float* xr = xbd + (wave * 16 + ln) * SL + quad * 8;
    const float bv = bias[d];

    // ---- issue the ENTIRE x row (16 float4) up front; pin with SB(0) -----
    float4 q[16];
#pragma unroll
    for (int s = 0; s < 8; ++s) {
        q[2 * s]     = *(const float4*)(xr + s * 32);
        q[2 * s + 1] = *(const float4*)(xr + s * 32 + 4);
    }
    __builtin_amdgcn_sched_barrier(0);      // loads stay issued here

    f16x8 axs[8];
#pragma unroll
    for (int s = 0; s < 4; ++s)             // waits first 8 loads only
        axs[s] = cvt8(q[2 * s], q[2 * s + 1]);

    bar_lgkm();                             // R tables ready; q1 in flight

    p1_work<0>(axs, Ry, buf0, wave, ln, quad);

    bar_lgkm();                             // buf0 ready; q1 still in flight

    p2_chunk<0>(buf0, Rx, xbd, obd, bv, igrp, jgrp, ln, quad);

#pragma unroll
    for (int s = 4; s < 8; ++s)             // q1 landed during p1/p2(c0)
        axs[s] = cvt8(q[2 * s], q[2 * s + 1]);

    p1_work<1>(axs, Ry, buf1, wave, ln, quad);

    bar_lgkm();                             // buf1 ready (out-stores may fly)

    p2_chunk<1>(buf1, Rx, xbd, obd, bv, igrp, jgrp, ln, quad);
}

// ---------------------------------------------------------------------------
// FALLBACK (if dynamic-LDS attribute fails): round-2 fused j-split kernel.
// ---------------------------------------------------------------------------
template<int J0>
__device__ __forceinline__ void phase1(
    const float* __restrict__ xr0, const float* __restrict__ xr1,
    const f16* __restrict__ R, f32x4 (&acc)[16], int ln, int quad)
{
    constexpr int QS = (J0 == 0) ? 4 : 8;
    float4 a0 = *(const float4*)xr0;
    float4 a1 = *(const float4*)(xr0 + 4);
    float4 b0 = *(const float4*)xr1;
    float4 b1 = *(const float4*)(xr1 + 4);

#pragma unroll
    for (int s = 0; s < QS; ++s) {
        const int q0 = s * 32;
        f16x8 af0 = cvt8(a0, a1);
        f16x8 af1 = cvt8(b0, b1);
        if (s + 1 < QS) {
            a0 = *(const float4*)(xr0 + q0 + 32);
            a1 = *(const float4*)(xr0 + q0 + 36);
            b0 = *(const float4*)(xr1 + q0 + 32);
            b1 = *(const float4*)(xr1 + q0 + 36);
        }
#pragma unroll
        for (int c8 = 0; c8 < 8; ++c8) {
            if (32 * s <= J0 + c8 * 16 + 15) {
                int j = J0 + c8 * 16 + ln;
                int s0 = 255 - j + q0 + quad * 8;
                int c = s0 & 7;
                f16x8 bf = *(const f16x8*)&R[c * RSTRIDE + (s0 - c)];
                acc[c8] = __builtin_amdgcn_mfma_f32_16x16x32_f16(
                    af0, bf, acc[c8], 0, 0, 0);
                acc[8 + c8] = __builtin_amdgcn_mfma_f32_16x16x32_f16(
                    af1, bf, acc[8 + c8], 0, 0, 0);
            }
        }
    }
}

__global__ __launch_bounds__(512, 4) void k_fused(
    const float* __restrict__ x, const f16* __restrict__ hxT,
    const f16* __restrict__ hyT, const float* __restrict__ bias,
    float* __restrict__ out)
{
    const int bd = blockIdx.x & 255;
    const int j0 = (blockIdx.x >> 8) << 7;
    const int d  = bd & 63;
    const int tid  = threadIdx.x;
    const int lane = tid & 63;
    const int wave = tid >> 6;
    const int ln   = lane & 15;
    const int quad = lane >> 4;

    __shared__ __align__(16) f16 tmp[128 * 256];
    __shared__ __align__(16) f16 R[8 * RSTRIDE];

    const float* xbd = x + (size_t)bd * (SL * SL);

    build_R<512>(R, hyT + d * 256, tid);

    f32x4 acc[16];
#pragma unroll
    for (int a = 0; a < 16; ++a) acc[a] = (f32x4){0.f, 0.f, 0.f, 0.f};

    __syncthreads();

    {
        const float* xr0 = xbd + (wave * 32 + ln) * SL + quad * 8;
        const float* xr1 = xr0 + 16 * SL;
        if (j0 == 0) phase1<0>(xr0, xr1, R, acc, ln, quad);
        else         phase1<128>(xr0, xr1, R, acc, ln, quad);

#pragma unroll
        for (int r = 0; r < 2; ++r)
#pragma unroll
            for (int c8 = 0; c8 < 8; ++c8) {
                int jl = c8 * 16 + ln;
                int pb = wave * 32 + r * 16 + quad * 4;
                f32x4 a = acc[r * 8 + c8];
                f16x4 v;
                v[0] = (f16)a[0]; v[1] = (f16)a[1];
                v[2] = (f16)a[2]; v[3] = (f16)a[3];
                *(f16x4*)&tmp[jl * 256 + (pb ^ ((jl & 7) << 3))] = v;
            }
    }

    __syncthreads();
    build_R<512>(R, hxT + d * 256, tid);
#pragma unroll
    for (int a = 0; a < 16; ++a) acc[a] = (f32x4){0.f, 0.f, 0.f, 0.f};
    __syncthreads();

    const int igrp = wave & 3;
    const int jgrp = wave >> 2;
    const int nst = (igrp + 1) * 2;
    for (int s = 0; s < nst; ++s) {
        const int p0 = s * 32;
        f16x8 af[4];
#pragma unroll
        for (int rt = 0; rt < 4; ++rt) {
            int jl = jgrp * 64 + rt * 16 + ln;
            int off = (p0 + quad * 8) ^ ((jl & 7) << 3);
            af[rt] = *(const f16x8*)&tmp[jl * 256 + off];
        }
#pragma unroll
        for (int ct = 0; ct < 4; ++ct) {
            if (p0 <= igrp * 64 + ct * 16 + 15) {
                int i = igrp * 64 + ct * 16 + ln;
                int s0 = 255 - i + p0 + quad * 8;
                int c = s0 & 7;
                f16x8 bf = *(const f16x8*)&R[c * RSTRIDE + (s0 - c)];
#pragma unroll
                for (int rt = 0; rt < 4; ++rt)
                    acc[rt * 4 + ct] = __builtin_amdgcn_mfma_f32_16x16x32_f16(
                        af[rt], bf, acc[rt * 4 + ct], 0, 0, 0);
            }
        }
    }

    const float bv = bias[d];
    const float sc = 1.0f / 512.0f;
    float* obd = out + (size_t)bd * (SL * SL);
#pragma unroll
    for (int rt = 0; rt < 4; ++rt)
#pragma unroll
        for (int ct = 0; ct < 4; ++ct) {
            int i = igrp * 64 + ct * 16 + ln;
            int j = j0 + jgrp * 64 + rt * 16 + quad * 4;
            f32x4 a = acc[rt * 4 + ct];
            float4 xv = *(const float4*)(xbd + i * SL + j);
            float4 o;
            o.x = a[0] * sc + xv.x * bv;
            o.y = a[1] * sc + xv.y * bv;
            o.z = a[2] * sc + xv.z * bv;
            o.w = a[3] * sc + xv.w * bv;
            *(float4*)(obd + i * SL + j) = o;
        }
}

extern "C" void kernel_launch(void* const* d_in, const int* in_sizes, int n_in,
                              void* d_out, int out_size, void* d_ws, size_t ws_size,
                              hipStream_t stream)
{
    (void)in_sizes; (void)n_in; (void)out_size; (void)ws_size;
    const float* x     = (const float*)d_in[0];
    const float* z     = (const float*)d_in[1];
    const float* Xw1   = (const float*)d_in[2];
    const float* Xb1   = (const float*)d_in[3];
    const float* Xw2   = (const float*)d_in[4];
    const float* Xb2   = (const float*)d_in[5];
    const float* Xw3   = (const float*)d_in[6];
    const float* Xb3   = (const float*)d_in[7];
    const float* Xwo   = (const float*)d_in[8];
    const float* Xfreq = (const float*)d_in[9];
    const float* Yw1   = (const float*)d_in[10];
    const float* Yb1   = (const float*)d_in[11];
    const float* Yw2   = (const float*)d_in[12];
    const float* Yb2   = (const float*)d_in[13];
    const float* Yw3   = (const float*)d_in[14];
    const float* Yb3   = (const float*)d_in[15];
    const float* Ywo   = (const float*)d_in[16];
    const float* Yfreq = (const float*)d_in[17];
    const float* bias  = (const float*)d_in[18];

    f16* hxT = (f16*)d_ws;                 // [64][256] f16
    f16* hyT = hxT + 64 * 256;             // [64][256] f16

    k_filters<<<dim3(256, 2), 64, 0, stream>>>(
        z, Xw1, Xb1, Xw2, Xb2, Xw3, Xb3, Xwo, Xfreq,
        Yw1, Yb1, Yw2, Yb2, Yw3, Yb3, Ywo, Yfreq, hxT, hyT);

    const int dyn_lds = (2 * 128 * 256 + 2 * 8 * RSTRIDE) * (int)sizeof(f16); // 141056
    static hipError_t attr_rc = hipFuncSetAttribute(
        (const void*)k_pipe, hipFuncAttributeMaxDynamicSharedMemorySize, dyn_lds);

    if (attr_rc == hipSuccess) {
        k_pipe<<<256, 1024, dyn_lds, stream>>>(x, hxT, hyT, bias, (float*)d_out);
    } else {
        k_fused<<<512, 512, 0, stream>>>(x, hxT, hyT, bias, (float*)d_out);
    }
}